// Round 2
// baseline (582.793 us; speedup 1.0000x reference)
//
#include <hip/hip_runtime.h>

typedef unsigned int uint32;

#define Bb 32
#define Pp 196
#define Dd 512
#define Hh 8
#define Uu 4
#define Cc 500

// Outputs (float32), concatenated flat in return order:
// out0: known_prompts   (B*C, 11, D) -> 32*500*11*512 = 90,112,000 elems
// out1: unknown_prompts (B, 7, D)    -> 114,688 elems @ 90,112,000
// out2: semantic_tokens (B, H, D)    -> 131,072 elems @ 90,226,688
#define OUT1_ELEM_OFF 90112000
#define OUT2_ELEM_OFF 90226688

__device__ __forceinline__ float dot4(float4 a, float4 b, float acc) {
    acc = fmaf(a.x, b.x, acc);
    acc = fmaf(a.y, b.y, acc);
    acc = fmaf(a.z, b.z, acc);
    acc = fmaf(a.w, b.w, acc);
    return acc;
}

// ---------------- Kernel 1: attention pooling -> semantic_tokens ----------------
// grid = B, block = 1024
__global__ __launch_bounds__(1024)
void k_pool(const float* __restrict__ patch, const float* __restrict__ query,
            float* __restrict__ st_out /* d_out + OUT2_ELEM_OFF */) {
    __shared__ float s_sc[Pp * Hh];      // scores, then weights
    __shared__ float s_m[Hh], s_inv[Hh];

    const int b = blockIdx.x;
    const int tid = threadIdx.x;
    const float* pb = patch + (size_t)b * Pp * Dd;

    // --- scores[p][h] = patch[b,p,:] . query[h,:] ---
    for (int idx = tid; idx < Pp * Hh; idx += 1024) {
        const int p = idx >> 3, h = idx & 7;
        const float4* pr = (const float4*)(pb + p * Dd);
        const float4* qr = (const float4*)(query + h * Dd);
        float acc = 0.f;
#pragma unroll 8
        for (int j = 0; j < Dd / 4; ++j) acc = dot4(pr[j], qr[j], acc);
        s_sc[idx] = acc;
    }
    __syncthreads();

    // --- softmax over p, per h ---
    if (tid < Hh) {
        float m = -1e30f;
        for (int p = 0; p < Pp; ++p) m = fmaxf(m, s_sc[p * Hh + tid]);
        float s = 0.f;
        for (int p = 0; p < Pp; ++p) s += __expf(s_sc[p * Hh + tid] - m);
        s_m[tid] = m;
        s_inv[tid] = 1.f / s;
    }
    __syncthreads();
    for (int idx = tid; idx < Pp * Hh; idx += 1024) {
        const int h = idx & 7;
        s_sc[idx] = __expf(s_sc[idx] - s_m[h]) * s_inv[h];
    }
    __syncthreads();

    // --- st[b,h,d] = sum_p w[p,h] * patch[b,p,d] ---
    // thread: d = tid & 511, handles h = hg*4 + {0,1,2,3} where hg = tid >> 9
    const int d = tid & 511;
    const int hg = tid >> 9;             // 0..1
    float a0 = 0.f, a1 = 0.f, a2 = 0.f, a3 = 0.f;
    for (int p = 0; p < Pp; ++p) {
        const float pv = pb[p * Dd + d];
        const float* w = &s_sc[p * Hh + hg * 4];
        a0 = fmaf(w[0], pv, a0);
        a1 = fmaf(w[1], pv, a1);
        a2 = fmaf(w[2], pv, a2);
        a3 = fmaf(w[3], pv, a3);
    }
    float* o = st_out + (size_t)b * Hh * Dd + (hg * 4) * Dd + d;
    o[0 * Dd] = a0;
    o[1 * Dd] = a1;
    o[2 * Dd] = a2;
    o[3 * Dd] = a3;
}

// ---------------- Kernel 2: dom + sem projections ----------------
// grid = 576 (512 sem blocks + 64 dom blocks), block = 256
__global__ __launch_bounds__(256)
void k_proj(const float* __restrict__ gf, const float* __restrict__ domW,
            const float* __restrict__ domb, const float* __restrict__ semW,
            const float* __restrict__ semb, const float* __restrict__ st,
            float* __restrict__ dom_ws, float* __restrict__ sem_ws) {
    const int blk = blockIdx.x;
    if (blk < 512) {
        // projected_sem[b,h,e] = sum_d st[b,h,d]*sem_W[h,e,d] + sem_b[h,e]
        const int tg = blk * 256 + threadIdx.x;       // 0..131071
        const int b = tg >> 12;
        const int rem = tg & 4095;
        const int h = rem >> 9;
        const int e = rem & 511;
        const float4* wr = (const float4*)(semW + (size_t)(h * Dd + e) * Dd);
        const float4* sr = (const float4*)(st + (size_t)(b * Hh + h) * Dd);
        float acc = semb[h * Dd + e];
#pragma unroll 8
        for (int j = 0; j < Dd / 4; ++j) acc = dot4(sr[j], wr[j], acc);
        sem_ws[(b * Hh + h) * Dd + e] = acc;
    } else {
        // projected_domain[b,e] = sum_d gf[b,d]*dom_W[e,d] + dom_b[e]
        const int tg = (blk - 512) * 256 + threadIdx.x;  // 0..16383
        const int b = tg >> 9;
        const int e = tg & 511;
        const float4* wr = (const float4*)(domW + (size_t)e * Dd);
        const float4* gr = (const float4*)(gf + (size_t)b * Dd);
        float acc = domb[e];
#pragma unroll 8
        for (int j = 0; j < Dd / 4; ++j) acc = dot4(gr[j], wr[j], acc);
        dom_ws[b * Dd + e] = acc;
    }
}

// ---------------- Kernel 3: prompt assembly (the 360 MB write) ----------------
// Rows are 11*512 floats = 5632 floats = 1408 uint4 (16B each); per token 128 uint4.
// grid = 1632 (1600 known: 32 b x 50 c-chunks of 10 rows; 32 unknown), block = 256
__global__ __launch_bounds__(256)
void k_assemble(const uint4* __restrict__ pre, const uint4* __restrict__ suf,
                const uint4* __restrict__ dom, const uint4* __restrict__ sem,
                const uint4* __restrict__ upre, const uint4* __restrict__ usuf,
                const uint4* __restrict__ ust,
                uint4* __restrict__ out0, uint4* __restrict__ out1) {
    const int blk = blockIdx.x;
    const int tid = threadIdx.x;
    if (blk < 1600) {
        const int b = blk / 50;
        const int chunk = blk % 50;
        __shared__ uint4 mid[1152];   // token1 = dom (128 uint4), tokens2-9 = sem (1024)
        for (int j = tid; j < 1152; j += 256)
            mid[j] = (j < 128) ? dom[b * 128 + j] : sem[b * 1024 + (j - 128)];
        __syncthreads();
        const int c0 = chunk * 10;
        for (int r = 0; r < 10; ++r) {
            const int c = c0 + r;
            uint4* row = out0 + (size_t)(b * Cc + c) * 1408;
            for (int i = tid; i < 1408; i += 256) {
                const int t = i >> 7;        // token id, uniform per wave (128 uint4/token)
                const int off = i & 127;
                uint4 v;
                if (t == 0) v = pre[c * 128 + off];
                else if (t == 10) v = suf[c * 128 + off];
                else v = mid[(t - 1) * 128 + off];
                row[i] = v;
            }
        }
    } else {
        const int b = blk - 1600;
        for (int i = tid; i < 896; i += 256) {   // 7*512 floats = 896 uint4
            const int t = i >> 7;
            const int off = i & 127;
            uint4 v;
            if (t == 0) v = upre[off];
            else if (t == 6) v = usuf[off];
            else if (t == 1) v = dom[b * 128 + off];
            else v = ust[(t - 2) * 128 + off];
            out1[b * 896 + i] = v;
        }
    }
}

extern "C" void kernel_launch(void* const* d_in, const int* in_sizes, int n_in,
                              void* d_out, int out_size, void* d_ws, size_t ws_size,
                              hipStream_t stream) {
    const float* patch = (const float*)d_in[0];   // (B,P,D)
    const float* gf    = (const float*)d_in[1];   // (B,D)
    const float* query = (const float*)d_in[2];   // (H,D)
    const float* domW  = (const float*)d_in[3];   // (D,D)
    const float* domb  = (const float*)d_in[4];   // (D,)
    const float* semW  = (const float*)d_in[5];   // (H,D,D)
    const float* semb  = (const float*)d_in[6];   // (H,D)
    const float* ust   = (const float*)d_in[7];   // (U,D)
    const float* pre   = (const float*)d_in[8];   // (C,1,D)
    const float* suf   = (const float*)d_in[9];   // (C,1,D)
    const float* upre  = (const float*)d_in[10];  // (1,D)
    const float* usuf  = (const float*)d_in[11];  // (1,D)

    float* out = (float*)d_out;
    float* st_out = out + OUT2_ELEM_OFF;          // semantic_tokens region

    float* dom_ws = (float*)d_ws;                 // B*D floats   = 64 KB
    float* sem_ws = dom_ws + Bb * Dd;             // B*H*D floats = 512 KB

    hipLaunchKernelGGL(k_pool, dim3(Bb), dim3(1024), 0, stream, patch, query, st_out);
    hipLaunchKernelGGL(k_proj, dim3(576), dim3(256), 0, stream,
                       gf, domW, domb, semW, semb, st_out, dom_ws, sem_ws);
    hipLaunchKernelGGL(k_assemble, dim3(1632), dim3(256), 0, stream,
                       (const uint4*)pre, (const uint4*)suf,
                       (const uint4*)dom_ws, (const uint4*)sem_ws,
                       (const uint4*)upre, (const uint4*)usuf, (const uint4*)ust,
                       (uint4*)out, (uint4*)(out + OUT1_ELEM_OFF));
}

// Round 3
// 480.408 us; speedup vs baseline: 1.2131x; 1.2131x over previous
//
#include <hip/hip_runtime.h>

typedef unsigned int uint32;
typedef uint32 v4u __attribute__((ext_vector_type(4)));

#define Bb 32
#define Pp 196
#define Dd 512
#define Hh 8
#define Uu 4
#define Cc 500

// Outputs (float32), concatenated flat:
// out0: known_prompts   (B*C, 11, D) -> 90,112,000 elems
// out1: unknown_prompts (B, 7, D)    -> 114,688 elems @ 90,112,000
// out2: semantic_tokens (B, H, D)    -> 131,072 elems @ 90,226,688
#define OUT1_ELEM_OFF 90112000
#define OUT2_ELEM_OFF 90226688

// ws layout (float element offsets; all 16B-aligned)
#define WS_SC   0          // scores (B,H,P)        = 50,176 floats
#define WS_PART 51200      // partials (B,8,H,D)    = 1,048,576 floats
#define WS_DOM  1099776    // projected_domain (B,D)= 16,384 floats
#define WS_SEM  1116160    // projected_sem (B,H,D) = 131,072 floats

__device__ __forceinline__ float dot4(float4 a, float4 b, float acc) {
    acc = fmaf(a.x, b.x, acc);
    acc = fmaf(a.y, b.y, acc);
    acc = fmaf(a.z, b.z, acc);
    acc = fmaf(a.w, b.w, acc);
    return acc;
}

// ---------------- K1: scores[b,h,p] = patch[b,p,:].query[h,:] ----------------
// grid = B*49 = 1568, block = 256 (4 waves, one p per wave)
__global__ __launch_bounds__(256)
void k_scores(const float* __restrict__ patch, const float* __restrict__ query,
              float* __restrict__ sc) {
    __shared__ float s_q[Hh * Dd];   // 16 KB
    const int b = blockIdx.x / 49;
    const int p0 = (blockIdx.x % 49) * 4;
    const int tid = threadIdx.x;
    for (int j = tid; j < Hh * Dd / 4; j += 256)
        ((float4*)s_q)[j] = ((const float4*)query)[j];
    __syncthreads();

    const int wave = tid >> 6, lane = tid & 63;
    const int p = p0 + wave;
    const float* pr = patch + ((size_t)b * Pp + p) * Dd + lane * 8;
    const float4 v0 = *(const float4*)pr;
    const float4 v1 = *(const float4*)(pr + 4);

    float out = 0.f;
#pragma unroll
    for (int h = 0; h < 8; ++h) {
        const float4 q0 = *(const float4*)&s_q[h * Dd + lane * 8];
        const float4 q1 = *(const float4*)&s_q[h * Dd + lane * 8 + 4];
        float a = dot4(v0, q0, 0.f);
        a = dot4(v1, q1, a);
#pragma unroll
        for (int m = 32; m >= 1; m >>= 1) a += __shfl_xor(a, m, 64);
        if (lane == h) out = a;
    }
    if (lane < 8) sc[((size_t)b * Hh + lane) * Pp + p] = out;
}

// ---------------- K2: softmax (in-block) + pooling partials ----------------
// grid = B*8 = 256 (b, p-chunk of 25), block = 256
__global__ __launch_bounds__(256)
void k_pool_part(const float* __restrict__ patch, const float* __restrict__ sc,
                 float* __restrict__ part) {
    __shared__ float s_w[Hh * Pp];   // scores -> weights, 6.3 KB
    const int b = blockIdx.x >> 3;
    const int pc = blockIdx.x & 7;
    const int tid = threadIdx.x;

    for (int j = tid; j < Hh * Pp; j += 256) s_w[j] = sc[(size_t)b * Hh * Pp + j];
    __syncthreads();

    // softmax over p for h = tid>>5, 32-lane group
    {
        const int h = tid >> 5, gl = tid & 31;
        float m = -1e30f;
        for (int p = gl; p < Pp; p += 32) m = fmaxf(m, s_w[h * Pp + p]);
#pragma unroll
        for (int mm = 16; mm >= 1; mm >>= 1) m = fmaxf(m, __shfl_xor(m, mm, 64));
        float s = 0.f;
        for (int p = gl; p < Pp; p += 32) s += __expf(s_w[h * Pp + p] - m);
#pragma unroll
        for (int mm = 16; mm >= 1; mm >>= 1) s += __shfl_xor(s, mm, 64);
        const float inv = 1.f / s;
        for (int p = gl; p < Pp; p += 32)
            s_w[h * Pp + p] = __expf(s_w[h * Pp + p] - m) * inv;  // disjoint p per thread
    }
    __syncthreads();

    // partial st over this p-chunk: thread = (hq = tid>>7 covers 4 h's, f = tid&127 float4 of D)
    const int f = tid & 127;
    const int hq = tid >> 7;
    const int pstart = pc * 25;
    const int pend = (pstart + 25 < Pp) ? pstart + 25 : Pp;
    float4 a0 = {0, 0, 0, 0}, a1 = a0, a2 = a0, a3 = a0;
    const float4* pb4 = (const float4*)(patch + (size_t)b * Pp * Dd);
    for (int p = pstart; p < pend; ++p) {
        const float4 pv = pb4[p * 128 + f];
        const float w0 = s_w[(hq * 4 + 0) * Pp + p];
        const float w1 = s_w[(hq * 4 + 1) * Pp + p];
        const float w2 = s_w[(hq * 4 + 2) * Pp + p];
        const float w3 = s_w[(hq * 4 + 3) * Pp + p];
        a0.x = fmaf(w0, pv.x, a0.x); a0.y = fmaf(w0, pv.y, a0.y);
        a0.z = fmaf(w0, pv.z, a0.z); a0.w = fmaf(w0, pv.w, a0.w);
        a1.x = fmaf(w1, pv.x, a1.x); a1.y = fmaf(w1, pv.y, a1.y);
        a1.z = fmaf(w1, pv.z, a1.z); a1.w = fmaf(w1, pv.w, a1.w);
        a2.x = fmaf(w2, pv.x, a2.x); a2.y = fmaf(w2, pv.y, a2.y);
        a2.z = fmaf(w2, pv.z, a2.z); a2.w = fmaf(w2, pv.w, a2.w);
        a3.x = fmaf(w3, pv.x, a3.x); a3.y = fmaf(w3, pv.y, a3.y);
        a3.z = fmaf(w3, pv.z, a3.z); a3.w = fmaf(w3, pv.w, a3.w);
    }
    float4* po = (float4*)part + ((size_t)b * 8 + pc) * 1024;   // 1024 float4 = H*D/4
    po[(hq * 4 + 0) * 128 + f] = a0;
    po[(hq * 4 + 1) * 128 + f] = a1;
    po[(hq * 4 + 2) * 128 + f] = a2;
    po[(hq * 4 + 3) * 128 + f] = a3;
}

// ---------------- K3: combine partials -> semantic_tokens (out2) ----------------
// grid = 128, block = 256; one float4 per thread over B*H*D/4 = 32768
__global__ __launch_bounds__(256)
void k_combine(const float* __restrict__ part, float* __restrict__ st) {
    const int idx = blockIdx.x * 256 + threadIdx.x;
    const int b = idx >> 10;
    const int r = idx & 1023;
    const float4* p4 = (const float4*)part;
    float4 a = {0, 0, 0, 0};
#pragma unroll
    for (int pc = 0; pc < 8; ++pc) {
        const float4 v = p4[((size_t)b * 8 + pc) * 1024 + r];
        a.x += v.x; a.y += v.y; a.z += v.z; a.w += v.w;
    }
    ((float4*)st)[idx] = a;
}

// ---------------- K4: dom + sem projections ----------------
// grid = 576 (512 sem + 64 dom), block = 256
__global__ __launch_bounds__(256)
void k_proj(const float* __restrict__ gf, const float* __restrict__ domW,
            const float* __restrict__ domb, const float* __restrict__ semW,
            const float* __restrict__ semb, const float* __restrict__ st,
            float* __restrict__ dom_ws, float* __restrict__ sem_ws) {
    const int blk = blockIdx.x;
    if (blk < 512) {
        const int tg = blk * 256 + threadIdx.x;
        const int b = tg >> 12;
        const int rem = tg & 4095;
        const int h = rem >> 9;
        const int e = rem & 511;
        const float4* wr = (const float4*)(semW + (size_t)(h * Dd + e) * Dd);
        const float4* sr = (const float4*)(st + (size_t)(b * Hh + h) * Dd);
        float acc = semb[h * Dd + e];
#pragma unroll 8
        for (int j = 0; j < Dd / 4; ++j) acc = dot4(sr[j], wr[j], acc);
        sem_ws[(b * Hh + h) * Dd + e] = acc;
    } else {
        const int tg = (blk - 512) * 256 + threadIdx.x;
        const int b = tg >> 9;
        const int e = tg & 511;
        const float4* wr = (const float4*)(domW + (size_t)e * Dd);
        const float4* gr = (const float4*)(gf + (size_t)b * Dd);
        float acc = domb[e];
#pragma unroll 8
        for (int j = 0; j < Dd / 4; ++j) acc = dot4(gr[j], wr[j], acc);
        dom_ws[b * Dd + e] = acc;
    }
}

// ---------------- K5: prompt assembly (360 MB streaming write) ----------------
// Rows: 11*512 fp32 = 1408 v4u; 128 v4u per token (waves token-aligned).
// grid = 1632 (1600 known: b x 50 c-chunks of 10 rows; 32 unknown), block = 256
__global__ __launch_bounds__(256)
void k_assemble(const v4u* __restrict__ pre, const v4u* __restrict__ suf,
                const v4u* __restrict__ dom, const v4u* __restrict__ sem,
                const v4u* __restrict__ upre, const v4u* __restrict__ usuf,
                const v4u* __restrict__ ust,
                v4u* __restrict__ out0, v4u* __restrict__ out1) {
    const int blk = blockIdx.x;
    const int tid = threadIdx.x;
    if (blk < 1600) {
        const int b = blk / 50;
        const int chunk = blk % 50;
        __shared__ v4u mid[1152];   // dom (128) + sem (1024), 18 KB
        for (int j = tid; j < 1152; j += 256)
            mid[j] = (j < 128) ? dom[b * 128 + j] : sem[b * 1024 + (j - 128)];
        __syncthreads();
        const int c0 = chunk * 10;
        for (int r = 0; r < 10; ++r) {
            const int c = c0 + r;
            v4u* row = out0 + (size_t)(b * Cc + c) * 1408;
            for (int i = tid; i < 1408; i += 256) {
                const int t = i >> 7;        // token id, wave-uniform
                const int off = i & 127;
                v4u v;
                if (t == 0) v = pre[c * 128 + off];
                else if (t == 10) v = suf[c * 128 + off];
                else v = mid[(t - 1) * 128 + off];
                __builtin_nontemporal_store(v, &row[i]);
            }
        }
    } else {
        const int b = blk - 1600;
        for (int i = tid; i < 896; i += 256) {   // 7*512 fp32 = 896 v4u
            const int t = i >> 7;
            const int off = i & 127;
            v4u v;
            if (t == 0) v = upre[off];
            else if (t == 6) v = usuf[off];
            else if (t == 1) v = dom[b * 128 + off];
            else v = ust[(t - 2) * 128 + off];
            __builtin_nontemporal_store(v, &out1[b * 896 + i]);
        }
    }
}

extern "C" void kernel_launch(void* const* d_in, const int* in_sizes, int n_in,
                              void* d_out, int out_size, void* d_ws, size_t ws_size,
                              hipStream_t stream) {
    const float* patch = (const float*)d_in[0];   // (B,P,D)
    const float* gf    = (const float*)d_in[1];   // (B,D)
    const float* query = (const float*)d_in[2];   // (H,D)
    const float* domW  = (const float*)d_in[3];   // (D,D)
    const float* domb  = (const float*)d_in[4];   // (D,)
    const float* semW  = (const float*)d_in[5];   // (H,D,D)
    const float* semb  = (const float*)d_in[6];   // (H,D)
    const float* ust   = (const float*)d_in[7];   // (U,D)
    const float* pre   = (const float*)d_in[8];   // (C,1,D)
    const float* suf   = (const float*)d_in[9];   // (C,1,D)
    const float* upre  = (const float*)d_in[10];  // (1,D)
    const float* usuf  = (const float*)d_in[11];  // (1,D)

    float* out = (float*)d_out;
    float* st_out = out + OUT2_ELEM_OFF;

    float* ws   = (float*)d_ws;
    float* sc_w = ws + WS_SC;
    float* part = ws + WS_PART;
    float* domp = ws + WS_DOM;
    float* semp = ws + WS_SEM;

    hipLaunchKernelGGL(k_scores, dim3(Bb * 49), dim3(256), 0, stream, patch, query, sc_w);
    hipLaunchKernelGGL(k_pool_part, dim3(Bb * 8), dim3(256), 0, stream, patch, sc_w, part);
    hipLaunchKernelGGL(k_combine, dim3(128), dim3(256), 0, stream, part, st_out);
    hipLaunchKernelGGL(k_proj, dim3(576), dim3(256), 0, stream,
                       gf, domW, domb, semW, semb, st_out, domp, semp);
    hipLaunchKernelGGL(k_assemble, dim3(1632), dim3(256), 0, stream,
                       (const v4u*)pre, (const v4u*)suf,
                       (const v4u*)domp, (const v4u*)semp,
                       (const v4u*)upre, (const v4u*)usuf, (const v4u*)ust,
                       (v4u*)out, (v4u*)(out + OUT1_ELEM_OFF));
}

// Round 4
// 441.155 us; speedup vs baseline: 1.3211x; 1.0890x over previous
//
#include <hip/hip_runtime.h>

typedef unsigned int uint32;
typedef uint32 v4u __attribute__((ext_vector_type(4)));

#define Bb 32
#define Pp 196
#define Dd 512
#define Hh 8
#define Uu 4
#define Cc 500

// Outputs (float32), concatenated flat:
// out0: known_prompts   (B*C, 11, D) -> 90,112,000 elems
// out1: unknown_prompts (B, 7, D)    -> 114,688 elems @ 90,112,000
// out2: semantic_tokens (B, H, D)    -> 131,072 elems @ 90,226,688
#define OUT1_ELEM_OFF 90112000
#define OUT2_ELEM_OFF 90226688

#define NPC 16   // p-chunks for pooling partials

// ws layout (float element offsets; all 16B-aligned)
#define WS_SC   0          // scores (B,H,P)          = 50,176 floats
#define WS_PART 51200      // partials (B,NPC,H,D)    = 2,097,152 floats
#define WS_DOM  2148352    // projected_domain (B,D)  = 16,384 floats
#define WS_SEM  2164736    // projected_sem (B,H,D)   = 131,072 floats

__device__ __forceinline__ float dot4(float4 a, float4 b, float acc) {
    acc = fmaf(a.x, b.x, acc);
    acc = fmaf(a.y, b.y, acc);
    acc = fmaf(a.z, b.z, acc);
    acc = fmaf(a.w, b.w, acc);
    return acc;
}

// ---------------- K1: scores[b,h,p] = patch[b,p,:].query[h,:] ----------------
// grid = B*49 = 1568, block = 256 (4 waves, one p per wave)
__global__ __launch_bounds__(256)
void k_scores(const float* __restrict__ patch, const float* __restrict__ query,
              float* __restrict__ sc) {
    __shared__ float s_q[Hh * Dd];   // 16 KB
    const int b = blockIdx.x / 49;
    const int p0 = (blockIdx.x % 49) * 4;
    const int tid = threadIdx.x;
    for (int j = tid; j < Hh * Dd / 4; j += 256)
        ((float4*)s_q)[j] = ((const float4*)query)[j];
    __syncthreads();

    const int wave = tid >> 6, lane = tid & 63;
    const int p = p0 + wave;
    const float* pr = patch + ((size_t)b * Pp + p) * Dd + lane * 8;
    const float4 v0 = *(const float4*)pr;
    const float4 v1 = *(const float4*)(pr + 4);

    float out = 0.f;
#pragma unroll
    for (int h = 0; h < 8; ++h) {
        const float4 q0 = *(const float4*)&s_q[h * Dd + lane * 8];
        const float4 q1 = *(const float4*)&s_q[h * Dd + lane * 8 + 4];
        float a = dot4(v0, q0, 0.f);
        a = dot4(v1, q1, a);
#pragma unroll
        for (int m = 32; m >= 1; m >>= 1) a += __shfl_xor(a, m, 64);
        if (lane == h) out = a;
    }
    if (lane < 8) sc[((size_t)b * Hh + lane) * Pp + p] = out;
}

// ---------------- K2: softmax (in-block, redundant per chunk) + pooling partials ----------------
// grid = B*NPC = 512 (b, p-chunk of 13), block = 256
__global__ __launch_bounds__(256)
void k_pool_part(const float* __restrict__ patch, const float* __restrict__ sc,
                 float* __restrict__ part) {
    __shared__ float s_w[Hh * Pp];   // scores -> weights, 6.3 KB
    const int b = blockIdx.x >> 4;
    const int pc = blockIdx.x & 15;
    const int tid = threadIdx.x;

    for (int j = tid; j < Hh * Pp; j += 256) s_w[j] = sc[(size_t)b * Hh * Pp + j];
    __syncthreads();

    // softmax over p for h = tid>>5, 32-lane group
    {
        const int h = tid >> 5, gl = tid & 31;
        float m = -1e30f;
        for (int p = gl; p < Pp; p += 32) m = fmaxf(m, s_w[h * Pp + p]);
#pragma unroll
        for (int mm = 16; mm >= 1; mm >>= 1) m = fmaxf(m, __shfl_xor(m, mm, 64));
        float s = 0.f;
        for (int p = gl; p < Pp; p += 32) s += __expf(s_w[h * Pp + p] - m);
#pragma unroll
        for (int mm = 16; mm >= 1; mm >>= 1) s += __shfl_xor(s, mm, 64);
        const float inv = 1.f / s;
        for (int p = gl; p < Pp; p += 32)
            s_w[h * Pp + p] = __expf(s_w[h * Pp + p] - m) * inv;  // disjoint p per thread
    }
    __syncthreads();

    // partial st over this p-chunk: thread = (hq = tid>>7, f = tid&127 float4 of D)
    const int f = tid & 127;
    const int hq = tid >> 7;
    const int pstart = pc * 13;
    const int pend = (pstart + 13 < Pp) ? pstart + 13 : Pp;
    float4 a0 = {0, 0, 0, 0}, a1 = a0, a2 = a0, a3 = a0;
    const float4* pb4 = (const float4*)(patch + (size_t)b * Pp * Dd);
    for (int p = pstart; p < pend; ++p) {
        const float4 pv = pb4[p * 128 + f];
        const float w0 = s_w[(hq * 4 + 0) * Pp + p];
        const float w1 = s_w[(hq * 4 + 1) * Pp + p];
        const float w2 = s_w[(hq * 4 + 2) * Pp + p];
        const float w3 = s_w[(hq * 4 + 3) * Pp + p];
        a0.x = fmaf(w0, pv.x, a0.x); a0.y = fmaf(w0, pv.y, a0.y);
        a0.z = fmaf(w0, pv.z, a0.z); a0.w = fmaf(w0, pv.w, a0.w);
        a1.x = fmaf(w1, pv.x, a1.x); a1.y = fmaf(w1, pv.y, a1.y);
        a1.z = fmaf(w1, pv.z, a1.z); a1.w = fmaf(w1, pv.w, a1.w);
        a2.x = fmaf(w2, pv.x, a2.x); a2.y = fmaf(w2, pv.y, a2.y);
        a2.z = fmaf(w2, pv.z, a2.z); a2.w = fmaf(w2, pv.w, a2.w);
        a3.x = fmaf(w3, pv.x, a3.x); a3.y = fmaf(w3, pv.y, a3.y);
        a3.z = fmaf(w3, pv.z, a3.z); a3.w = fmaf(w3, pv.w, a3.w);
    }
    float4* po = (float4*)part + ((size_t)b * NPC + pc) * 1024;   // 1024 float4 = H*D/4
    po[(hq * 4 + 0) * 128 + f] = a0;
    po[(hq * 4 + 1) * 128 + f] = a1;
    po[(hq * 4 + 2) * 128 + f] = a2;
    po[(hq * 4 + 3) * 128 + f] = a3;
}

// ---------------- K3: combine partials -> semantic_tokens (out2) ----------------
// grid = 128, block = 256; one float4 per thread over B*H*D/4 = 32768
__global__ __launch_bounds__(256)
void k_combine(const float* __restrict__ part, float* __restrict__ st) {
    const int idx = blockIdx.x * 256 + threadIdx.x;
    const int b = idx >> 10;
    const int r = idx & 1023;
    const float4* p4 = (const float4*)part;
    float4 a = {0, 0, 0, 0};
#pragma unroll
    for (int pc = 0; pc < NPC; ++pc) {
        const float4 v = p4[((size_t)b * NPC + pc) * 1024 + r];
        a.x += v.x; a.y += v.y; a.z += v.z; a.w += v.w;
    }
    ((float4*)st)[idx] = a;
}

// ---------------- K4: dom + sem projections (LDS-tiled, coalesced) ----------------
// grid = 192: blk<128 -> sem (h = blk>>4, e-tile of 32); blk>=128 -> dom (64 blocks)
// sem block: stage semW[h, e0:e0+32, :] (65.7 KB, stride 513) + st[:, h, :] (65.7 KB)
// thread: 2b x 2e register tile; 1024 outputs per block.
#define PJS 513
__global__ __launch_bounds__(256)
void k_proj(const float* __restrict__ gf, const float* __restrict__ domW,
            const float* __restrict__ domb, const float* __restrict__ semW,
            const float* __restrict__ semb, const float* __restrict__ st,
            float* __restrict__ dom_ws, float* __restrict__ sem_ws) {
    __shared__ float s_w[32 * PJS];    // 65,664 B
    __shared__ float s_st[32 * PJS];   // 65,664 B
    const int blk = blockIdx.x;
    const int tid = threadIdx.x;
    if (blk < 128) {
        const int h = blk >> 4;
        const int e0 = (blk & 15) * 32;
        // stage: 32 rows x 128 float4 each, coalesced
        for (int g = tid; g < 32 * 128; g += 256) {
            const int r = g >> 7, c4 = g & 127;
            const float4 w = ((const float4*)semW)[((size_t)(h * Dd + e0 + r)) * 128 + c4];
            float* dw = &s_w[r * PJS + c4 * 4];
            dw[0] = w.x; dw[1] = w.y; dw[2] = w.z; dw[3] = w.w;
            const float4 s = ((const float4*)st)[((size_t)(r * Hh + h)) * 128 + c4];
            float* ds = &s_st[r * PJS + c4 * 4];
            ds[0] = s.x; ds[1] = s.y; ds[2] = s.z; ds[3] = s.w;
        }
        __syncthreads();
        const int pe = tid & 15;       // e = e0 + 2*pe + {0,1}
        const int pb = tid >> 4;       // b = 2*pb + {0,1}
        const float* w0r = &s_w[(2 * pe) * PJS];
        const float* w1r = &s_w[(2 * pe + 1) * PJS];
        const float* s0r = &s_st[(2 * pb) * PJS];
        const float* s1r = &s_st[(2 * pb + 1) * PJS];
        float a00 = 0.f, a01 = 0.f, a10 = 0.f, a11 = 0.f;
#pragma unroll 8
        for (int d = 0; d < Dd; ++d) {
            const float w0 = w0r[d], w1 = w1r[d];
            const float s0 = s0r[d], s1 = s1r[d];
            a00 = fmaf(s0, w0, a00);
            a01 = fmaf(s0, w1, a01);
            a10 = fmaf(s1, w0, a10);
            a11 = fmaf(s1, w1, a11);
        }
        const int e_ = e0 + 2 * pe;
        const float b0 = semb[h * Dd + e_], b1 = semb[h * Dd + e_ + 1];
        float* o0 = &sem_ws[((2 * pb) * Hh + h) * Dd + e_];
        float* o1 = &sem_ws[((2 * pb + 1) * Hh + h) * Dd + e_];
        o0[0] = a00 + b0; o0[1] = a01 + b1;
        o1[0] = a10 + b0; o1[1] = a11 + b1;
    } else {
        // projected_domain[b,e] = sum_d gf[b,d]*dom_W[e,d] + dom_b[e]
        const int tg = (blk - 128) * 256 + tid;   // 0..16383
        const int b = tg >> 9;
        const int e = tg & 511;
        const float4* wr = (const float4*)(domW + (size_t)e * Dd);
        const float4* gr = (const float4*)(gf + (size_t)b * Dd);
        float acc = domb[e];
#pragma unroll 8
        for (int j = 0; j < Dd / 4; ++j) acc = dot4(gr[j], wr[j], acc);
        dom_ws[b * Dd + e] = acc;
    }
}

// ---------------- K5: prompt assembly (360 MB streaming write) ----------------
// Rows: 11*512 fp32 = 1408 v4u; 128 v4u per token (waves token-aligned).
// grid = 1632 (1600 known: b x 50 c-chunks of 10 rows; 32 unknown), block = 256
__global__ __launch_bounds__(256)
void k_assemble(const v4u* __restrict__ pre, const v4u* __restrict__ suf,
                const v4u* __restrict__ dom, const v4u* __restrict__ sem,
                const v4u* __restrict__ upre, const v4u* __restrict__ usuf,
                const v4u* __restrict__ ust,
                v4u* __restrict__ out0, v4u* __restrict__ out1) {
    const int blk = blockIdx.x;
    const int tid = threadIdx.x;
    if (blk < 1600) {
        const int b = blk / 50;
        const int chunk = blk % 50;
        __shared__ v4u mid[1152];   // dom (128) + sem (1024), 18 KB
        for (int j = tid; j < 1152; j += 256)
            mid[j] = (j < 128) ? dom[b * 128 + j] : sem[b * 1024 + (j - 128)];
        __syncthreads();
        const int c0 = chunk * 10;
        for (int r = 0; r < 10; ++r) {
            const int c = c0 + r;
            v4u* row = out0 + (size_t)(b * Cc + c) * 1408;
            for (int i = tid; i < 1408; i += 256) {
                const int t = i >> 7;        // token id, wave-uniform
                const int off = i & 127;
                v4u v;
                if (t == 0) v = pre[c * 128 + off];
                else if (t == 10) v = suf[c * 128 + off];
                else v = mid[(t - 1) * 128 + off];
                __builtin_nontemporal_store(v, &row[i]);
            }
        }
    } else {
        const int b = blk - 1600;
        for (int i = tid; i < 896; i += 256) {   // 7*512 fp32 = 896 v4u
            const int t = i >> 7;
            const int off = i & 127;
            v4u v;
            if (t == 0) v = upre[off];
            else if (t == 6) v = usuf[off];
            else if (t == 1) v = dom[b * 128 + off];
            else v = ust[(t - 2) * 128 + off];
            __builtin_nontemporal_store(v, &out1[b * 896 + i]);
        }
    }
}

extern "C" void kernel_launch(void* const* d_in, const int* in_sizes, int n_in,
                              void* d_out, int out_size, void* d_ws, size_t ws_size,
                              hipStream_t stream) {
    const float* patch = (const float*)d_in[0];   // (B,P,D)
    const float* gf    = (const float*)d_in[1];   // (B,D)
    const float* query = (const float*)d_in[2];   // (H,D)
    const float* domW  = (const float*)d_in[3];   // (D,D)
    const float* domb  = (const float*)d_in[4];   // (D,)
    const float* semW  = (const float*)d_in[5];   // (H,D,D)
    const float* semb  = (const float*)d_in[6];   // (H,D)
    const float* ust   = (const float*)d_in[7];   // (U,D)
    const float* pre   = (const float*)d_in[8];   // (C,1,D)
    const float* suf   = (const float*)d_in[9];   // (C,1,D)
    const float* upre  = (const float*)d_in[10];  // (1,D)
    const float* usuf  = (const float*)d_in[11];  // (1,D)

    float* out = (float*)d_out;
    float* st_out = out + OUT2_ELEM_OFF;

    float* ws   = (float*)d_ws;
    float* sc_w = ws + WS_SC;
    float* part = ws + WS_PART;
    float* domp = ws + WS_DOM;
    float* semp = ws + WS_SEM;

    hipLaunchKernelGGL(k_scores, dim3(Bb * 49), dim3(256), 0, stream, patch, query, sc_w);
    hipLaunchKernelGGL(k_pool_part, dim3(Bb * NPC), dim3(256), 0, stream, patch, sc_w, part);
    hipLaunchKernelGGL(k_combine, dim3(128), dim3(256), 0, stream, part, st_out);
    hipLaunchKernelGGL(k_proj, dim3(192), dim3(256), 0, stream,
                       gf, domW, domb, semW, semb, st_out, domp, semp);
    hipLaunchKernelGGL(k_assemble, dim3(1632), dim3(256), 0, stream,
                       (const v4u*)pre, (const v4u*)suf,
                       (const v4u*)domp, (const v4u*)semp,
                       (const v4u*)upre, (const v4u*)usuf, (const v4u*)ust,
                       (v4u*)out, (v4u*)(out + OUT1_ELEM_OFF));
}

// Round 5
// 434.621 us; speedup vs baseline: 1.3409x; 1.0150x over previous
//
#include <hip/hip_runtime.h>

typedef unsigned int uint32;
typedef uint32 v4u __attribute__((ext_vector_type(4)));

#define Bb 32
#define Pp 196
#define Dd 512
#define Hh 8
#define Uu 4
#define Cc 500

// Outputs (float32), concatenated flat:
// out0: known_prompts   (B*C, 11, D) -> 90,112,000 elems
// out1: unknown_prompts (B, 7, D)    -> 114,688 elems @ 90,112,000
// out2: semantic_tokens (B, H, D)    -> 131,072 elems @ 90,226,688
#define OUT1_ELEM_OFF 90112000
#define OUT2_ELEM_OFF 90226688

#define NPC 16   // p-chunks for pooling partials

// ws layout (float element offsets; all 16B-aligned)
#define WS_SC   0          // scores (B,H,P)          = 50,176 floats
#define WS_PART 51200      // partials (B,NPC,H,D)    = 2,097,152 floats
#define WS_DOM  2148352    // projected_domain (B,D)  = 16,384 floats
#define WS_SEM  2164736    // projected_sem (B,H,D)   = 131,072 floats

__device__ __forceinline__ float dot4(float4 a, float4 b, float acc) {
    acc = fmaf(a.x, b.x, acc);
    acc = fmaf(a.y, b.y, acc);
    acc = fmaf(a.z, b.z, acc);
    acc = fmaf(a.w, b.w, acc);
    return acc;
}

// ---------------- K1: scores[b,h,p] = patch[b,p,:].query[h,:] ----------------
// grid = B*49 = 1568, block = 256 (4 waves, one p per wave)
__global__ __launch_bounds__(256)
void k_scores(const float* __restrict__ patch, const float* __restrict__ query,
              float* __restrict__ sc) {
    __shared__ float s_q[Hh * Dd];   // 16 KB
    const int b = blockIdx.x / 49;
    const int p0 = (blockIdx.x % 49) * 4;
    const int tid = threadIdx.x;
    for (int j = tid; j < Hh * Dd / 4; j += 256)
        ((float4*)s_q)[j] = ((const float4*)query)[j];
    __syncthreads();

    const int wave = tid >> 6, lane = tid & 63;
    const int p = p0 + wave;
    const float* pr = patch + ((size_t)b * Pp + p) * Dd + lane * 8;
    const float4 v0 = *(const float4*)pr;
    const float4 v1 = *(const float4*)(pr + 4);

    float out = 0.f;
#pragma unroll
    for (int h = 0; h < 8; ++h) {
        const float4 q0 = *(const float4*)&s_q[h * Dd + lane * 8];
        const float4 q1 = *(const float4*)&s_q[h * Dd + lane * 8 + 4];
        float a = dot4(v0, q0, 0.f);
        a = dot4(v1, q1, a);
#pragma unroll
        for (int m = 32; m >= 1; m >>= 1) a += __shfl_xor(a, m, 64);
        if (lane == h) out = a;
    }
    if (lane < 8) sc[((size_t)b * Hh + lane) * Pp + p] = out;
}

// ---------------- K2: softmax (in-block, redundant per chunk) + pooling partials ----------------
// grid = B*NPC = 512 (b, p-chunk of 13), block = 256
__global__ __launch_bounds__(256)
void k_pool_part(const float* __restrict__ patch, const float* __restrict__ sc,
                 float* __restrict__ part) {
    __shared__ float s_w[Hh * Pp];   // scores -> weights, 6.3 KB
    const int b = blockIdx.x >> 4;
    const int pc = blockIdx.x & 15;
    const int tid = threadIdx.x;

    for (int j = tid; j < Hh * Pp; j += 256) s_w[j] = sc[(size_t)b * Hh * Pp + j];
    __syncthreads();

    // softmax over p for h = tid>>5, 32-lane group
    {
        const int h = tid >> 5, gl = tid & 31;
        float m = -1e30f;
        for (int p = gl; p < Pp; p += 32) m = fmaxf(m, s_w[h * Pp + p]);
#pragma unroll
        for (int mm = 16; mm >= 1; mm >>= 1) m = fmaxf(m, __shfl_xor(m, mm, 64));
        float s = 0.f;
        for (int p = gl; p < Pp; p += 32) s += __expf(s_w[h * Pp + p] - m);
#pragma unroll
        for (int mm = 16; mm >= 1; mm >>= 1) s += __shfl_xor(s, mm, 64);
        const float inv = 1.f / s;
        for (int p = gl; p < Pp; p += 32)
            s_w[h * Pp + p] = __expf(s_w[h * Pp + p] - m) * inv;  // disjoint p per thread
    }
    __syncthreads();

    // partial st over this p-chunk: thread = (hq = tid>>7, f = tid&127 float4 of D)
    const int f = tid & 127;
    const int hq = tid >> 7;
    const int pstart = pc * 13;
    const int pend = (pstart + 13 < Pp) ? pstart + 13 : Pp;
    float4 a0 = {0, 0, 0, 0}, a1 = a0, a2 = a0, a3 = a0;
    const float4* pb4 = (const float4*)(patch + (size_t)b * Pp * Dd);
    for (int p = pstart; p < pend; ++p) {
        const float4 pv = pb4[p * 128 + f];
        const float w0 = s_w[(hq * 4 + 0) * Pp + p];
        const float w1 = s_w[(hq * 4 + 1) * Pp + p];
        const float w2 = s_w[(hq * 4 + 2) * Pp + p];
        const float w3 = s_w[(hq * 4 + 3) * Pp + p];
        a0.x = fmaf(w0, pv.x, a0.x); a0.y = fmaf(w0, pv.y, a0.y);
        a0.z = fmaf(w0, pv.z, a0.z); a0.w = fmaf(w0, pv.w, a0.w);
        a1.x = fmaf(w1, pv.x, a1.x); a1.y = fmaf(w1, pv.y, a1.y);
        a1.z = fmaf(w1, pv.z, a1.z); a1.w = fmaf(w1, pv.w, a1.w);
        a2.x = fmaf(w2, pv.x, a2.x); a2.y = fmaf(w2, pv.y, a2.y);
        a2.z = fmaf(w2, pv.z, a2.z); a2.w = fmaf(w2, pv.w, a2.w);
        a3.x = fmaf(w3, pv.x, a3.x); a3.y = fmaf(w3, pv.y, a3.y);
        a3.z = fmaf(w3, pv.z, a3.z); a3.w = fmaf(w3, pv.w, a3.w);
    }
    float4* po = (float4*)part + ((size_t)b * NPC + pc) * 1024;   // 1024 float4 = H*D/4
    po[(hq * 4 + 0) * 128 + f] = a0;
    po[(hq * 4 + 1) * 128 + f] = a1;
    po[(hq * 4 + 2) * 128 + f] = a2;
    po[(hq * 4 + 3) * 128 + f] = a3;
}

// ---------------- K3: combine partials -> semantic_tokens (out2) ----------------
// grid = 128, block = 256; one float4 per thread over B*H*D/4 = 32768
__global__ __launch_bounds__(256)
void k_combine(const float* __restrict__ part, float* __restrict__ st) {
    const int idx = blockIdx.x * 256 + threadIdx.x;
    const int b = idx >> 10;
    const int r = idx & 1023;
    const float4* p4 = (const float4*)part;
    float4 a = {0, 0, 0, 0};
#pragma unroll
    for (int pc = 0; pc < NPC; ++pc) {
        const float4 v = p4[((size_t)b * NPC + pc) * 1024 + r];
        a.x += v.x; a.y += v.y; a.z += v.z; a.w += v.w;
    }
    ((float4*)st)[idx] = a;
}

// ---------------- K4: dom + sem projections (LDS-tiled, coalesced) ----------------
// grid = 192: blk<128 -> sem (h = blk>>4, e-tile of 32); blk>=128 -> dom (64 blocks)
#define PJS 513
__global__ __launch_bounds__(256)
void k_proj(const float* __restrict__ gf, const float* __restrict__ domW,
            const float* __restrict__ domb, const float* __restrict__ semW,
            const float* __restrict__ semb, const float* __restrict__ st,
            float* __restrict__ dom_ws, float* __restrict__ sem_ws) {
    __shared__ float s_w[32 * PJS];    // 65,664 B
    __shared__ float s_st[32 * PJS];   // 65,664 B
    const int blk = blockIdx.x;
    const int tid = threadIdx.x;
    if (blk < 128) {
        const int h = blk >> 4;
        const int e0 = (blk & 15) * 32;
        for (int g = tid; g < 32 * 128; g += 256) {
            const int r = g >> 7, c4 = g & 127;
            const float4 w = ((const float4*)semW)[((size_t)(h * Dd + e0 + r)) * 128 + c4];
            float* dw = &s_w[r * PJS + c4 * 4];
            dw[0] = w.x; dw[1] = w.y; dw[2] = w.z; dw[3] = w.w;
            const float4 s = ((const float4*)st)[((size_t)(r * Hh + h)) * 128 + c4];
            float* ds = &s_st[r * PJS + c4 * 4];
            ds[0] = s.x; ds[1] = s.y; ds[2] = s.z; ds[3] = s.w;
        }
        __syncthreads();
        const int pe = tid & 15;       // e = e0 + 2*pe + {0,1}
        const int pb = tid >> 4;       // b = 2*pb + {0,1}
        const float* w0r = &s_w[(2 * pe) * PJS];
        const float* w1r = &s_w[(2 * pe + 1) * PJS];
        const float* s0r = &s_st[(2 * pb) * PJS];
        const float* s1r = &s_st[(2 * pb + 1) * PJS];
        float a00 = 0.f, a01 = 0.f, a10 = 0.f, a11 = 0.f;
#pragma unroll 8
        for (int d = 0; d < Dd; ++d) {
            const float w0 = w0r[d], w1 = w1r[d];
            const float s0 = s0r[d], s1 = s1r[d];
            a00 = fmaf(s0, w0, a00);
            a01 = fmaf(s0, w1, a01);
            a10 = fmaf(s1, w0, a10);
            a11 = fmaf(s1, w1, a11);
        }
        const int e_ = e0 + 2 * pe;
        const float b0 = semb[h * Dd + e_], b1 = semb[h * Dd + e_ + 1];
        float* o0 = &sem_ws[((2 * pb) * Hh + h) * Dd + e_];
        float* o1 = &sem_ws[((2 * pb + 1) * Hh + h) * Dd + e_];
        o0[0] = a00 + b0; o0[1] = a01 + b1;
        o1[0] = a10 + b0; o1[1] = a11 + b1;
    } else {
        const int tg = (blk - 128) * 256 + tid;   // 0..16383
        const int b = tg >> 9;
        const int e = tg & 511;
        const float4* wr = (const float4*)(domW + (size_t)e * Dd);
        const float4* gr = (const float4*)(gf + (size_t)b * Dd);
        float acc = domb[e];
#pragma unroll 8
        for (int j = 0; j < Dd / 4; ++j) acc = dot4(gr[j], wr[j], acc);
        dom_ws[b * Dd + e] = acc;
    }
}

// ---------------- K5: prompt assembly (360 MB streaming write, fill-shaped) ----------------
// One output row per block, no LDS, regular stores.
// grid = 16032: blk<16000 -> known row (b = blk/500, c = blk%500, row index == blk);
//               blk>=16000 -> unknown prompts for b = blk-16000.
// Known row = 1408 v4u: token t = i>>7 (wave-uniform), 0=pre, 1=dom, 2..9=sem, 10=suf.
__global__ __launch_bounds__(256)
void k_assemble(const v4u* __restrict__ pre, const v4u* __restrict__ suf,
                const v4u* __restrict__ dom, const v4u* __restrict__ sem,
                const v4u* __restrict__ upre, const v4u* __restrict__ usuf,
                const v4u* __restrict__ ust,
                v4u* __restrict__ out0, v4u* __restrict__ out1) {
    const int blk = blockIdx.x;
    const int tid = threadIdx.x;
    if (blk < 16000) {
        const int b = blk / 500;
        const int c = blk % 500;
        v4u* row = out0 + (size_t)blk * 1408;
#pragma unroll
        for (int k = 0; k < 6; ++k) {
            const int i = tid + k * 256;
            if (k < 5 || i < 1408) {
                const int t = i >> 7;        // wave-uniform
                const int off = i & 127;
                v4u v;
                if (t == 0) v = pre[c * 128 + off];
                else if (t == 10) v = suf[c * 128 + off];
                else if (t == 1) v = dom[b * 128 + off];
                else v = sem[b * 1024 + (t - 2) * 128 + off];
                row[i] = v;
            }
        }
    } else {
        const int b = blk - 16000;
#pragma unroll
        for (int k = 0; k < 4; ++k) {
            const int i = tid + k * 256;
            if (k < 3 || i < 896) {          // 7*512 fp32 = 896 v4u
                const int t = i >> 7;
                const int off = i & 127;
                v4u v;
                if (t == 0) v = upre[off];
                else if (t == 6) v = usuf[off];
                else if (t == 1) v = dom[b * 128 + off];
                else v = ust[(t - 2) * 128 + off];
                out1[b * 896 + i] = v;
            }
        }
    }
}

extern "C" void kernel_launch(void* const* d_in, const int* in_sizes, int n_in,
                              void* d_out, int out_size, void* d_ws, size_t ws_size,
                              hipStream_t stream) {
    const float* patch = (const float*)d_in[0];   // (B,P,D)
    const float* gf    = (const float*)d_in[1];   // (B,D)
    const float* query = (const float*)d_in[2];   // (H,D)
    const float* domW  = (const float*)d_in[3];   // (D,D)
    const float* domb  = (const float*)d_in[4];   // (D,)
    const float* semW  = (const float*)d_in[5];   // (H,D,D)
    const float* semb  = (const float*)d_in[6];   // (H,D)
    const float* ust   = (const float*)d_in[7];   // (U,D)
    const float* pre   = (const float*)d_in[8];   // (C,1,D)
    const float* suf   = (const float*)d_in[9];   // (C,1,D)
    const float* upre  = (const float*)d_in[10];  // (1,D)
    const float* usuf  = (const float*)d_in[11];  // (1,D)

    float* out = (float*)d_out;
    float* st_out = out + OUT2_ELEM_OFF;

    float* ws   = (float*)d_ws;
    float* sc_w = ws + WS_SC;
    float* part = ws + WS_PART;
    float* domp = ws + WS_DOM;
    float* semp = ws + WS_SEM;

    hipLaunchKernelGGL(k_scores, dim3(Bb * 49), dim3(256), 0, stream, patch, query, sc_w);
    hipLaunchKernelGGL(k_pool_part, dim3(Bb * NPC), dim3(256), 0, stream, patch, sc_w, part);
    hipLaunchKernelGGL(k_combine, dim3(128), dim3(256), 0, stream, part, st_out);
    hipLaunchKernelGGL(k_proj, dim3(192), dim3(256), 0, stream,
                       gf, domW, domb, semW, semb, st_out, domp, semp);
    hipLaunchKernelGGL(k_assemble, dim3(16032), dim3(256), 0, stream,
                       (const v4u*)pre, (const v4u*)suf,
                       (const v4u*)domp, (const v4u*)semp,
                       (const v4u*)upre, (const v4u*)usuf, (const v4u*)ust,
                       (v4u*)out, (v4u*)(out + OUT1_ELEM_OFF));
}